// Round 2
// baseline (719.239 us; speedup 1.0000x reference)
//
#include <hip/hip_runtime.h>
#include <cstddef>

#define Nn 1024
#define Bb 32
#define Ff 128
#define Vv 32768            // B*N
#define MAT 33554432        // B*N*N
#define OUT_OFF 0
#define AC_OFF 8192
#define OA_OFF (8192 + 33554432)
#define MC_OFF (OA_OFF + 128)
#define OR_OFF (MC_OFF + 1)
#define EPSf 1e-15f
#define MUf 0.01f

__device__ __forceinline__ float wave_sum(float v) {
    #pragma unroll
    for (int off = 32; off; off >>= 1) v += __shfl_xor(v, off, 64);
    return v;
}
__device__ __forceinline__ float wave_max(float v) {
    #pragma unroll
    for (int off = 32; off; off >>= 1) v = fmaxf(v, __shfl_xor(v, off, 64));
    return v;
}

// ---- K1: row sums of adj -> d_flat. wave per row, 4 rows/block ----
__global__ void k_rowsum(const float* __restrict__ adj, float* __restrict__ dflat) {
    int w = threadIdx.x >> 6, lane = threadIdx.x & 63;
    int row = blockIdx.x * 4 + w;          // 0..32767
    const float* r = adj + (size_t)row * Nn;
    float acc = 0.f;
    #pragma unroll
    for (int cc = 0; cc < 4; ++cc) {
        float4 v = *(const float4*)(r + cc * 256 + (lane << 2));
        acc += v.x + v.y + v.z + v.w;
    }
    acc = wave_sum(acc);
    if (lane == 0) dflat[row] = acc;
}

// ---- K2: per-node vectors ----
__global__ void k_vectors(const float* __restrict__ s_in, const float* __restrict__ dflat,
                          float* __restrict__ s0a, float* __restrict__ s1a,
                          float* __restrict__ ua, float* __restrict__ uoda,
                          float* __restrict__ d2a, float* __restrict__ ddera) {
    int idx = blockIdx.x * 256 + threadIdx.x;   // < 32768
    float l0 = s_in[2 * idx], l1 = s_in[2 * idx + 1];
    float m = fmaxf(l0, l1);
    float e0 = __expf(l0 - m), e1 = __expf(l1 - m);
    float Z = e0 + e1;
    s0a[idx] = e0 / Z; s1a[idx] = e1 / Z;
    float u = (l1 > l0) ? -0.03125f : 0.03125f;   // +-1/sqrt(1024), argmax==1 -> negative
    float df = dflat[idx];
    float d2 = sqrtf(df + EPSf) + EPSf;
    float uod = u / d2;
    ua[idx] = u; uoda[idx] = uod; d2a[idx] = d2;
    ddera[idx] = -0.5f * d2 / (df + EPSf);
}

// ---- K3: per-row matvecs r1=A.uod r2=A.u q1=A.s0 q2=A.s1. wave per row ----
__global__ void k_matvec(const float* __restrict__ adj,
                         const float* __restrict__ uoda, const float* __restrict__ ua,
                         const float* __restrict__ s0a, const float* __restrict__ s1a,
                         float* __restrict__ r1a, float* __restrict__ r2a,
                         float* __restrict__ q1a, float* __restrict__ q2a) {
    int w = threadIdx.x >> 6, lane = threadIdx.x & 63;
    int row = blockIdx.x * 4 + w;
    int b = row >> 10;
    const float* r = adj + (size_t)row * Nn;
    const float* uodB = uoda + b * Nn;
    const float* uB = ua + b * Nn;
    const float* s0B = s0a + b * Nn;
    const float* s1B = s1a + b * Nn;
    float a1 = 0.f, a2 = 0.f, a3 = 0.f, a4 = 0.f;
    #pragma unroll
    for (int cc = 0; cc < 4; ++cc) {
        int j0 = cc * 256 + (lane << 2);
        float4 av = *(const float4*)(r + j0);
        float4 uo = *(const float4*)(uodB + j0);
        float4 uu = *(const float4*)(uB + j0);
        float4 v0 = *(const float4*)(s0B + j0);
        float4 v1 = *(const float4*)(s1B + j0);
        a1 += av.x * uo.x + av.y * uo.y + av.z * uo.z + av.w * uo.w;
        a2 += av.x * uu.x + av.y * uu.y + av.z * uu.z + av.w * uu.w;
        a3 += av.x * v0.x + av.y * v0.y + av.z * v0.z + av.w * v0.w;
        a4 += av.x * v1.x + av.y * v1.y + av.z * v1.z + av.w * v1.w;
    }
    a1 = wave_sum(a1); a2 = wave_sum(a2); a3 = wave_sum(a3); a4 = wave_sum(a4);
    if (lane == 0) { r1a[row] = a1; r2a[row] = a2; q1a[row] = a3; q2a[row] = a4; }
}

// ---- K4: per-batch reductions -> f, coefP, m8f, out_adj, loss parts ----
__global__ void k_batchred(const float* __restrict__ dflat, const float* __restrict__ s0a,
                           const float* __restrict__ s1a, const float* __restrict__ ua,
                           const float* __restrict__ uoda, const float* __restrict__ d2a,
                           const float* __restrict__ r1a, const float* __restrict__ r2a,
                           const float* __restrict__ q1a, const float* __restrict__ q2a,
                           float* __restrict__ outp, float* __restrict__ coefP,
                           float* __restrict__ m8f, float* __restrict__ mcp,
                           float* __restrict__ orp) {
    int b = blockIdx.x, t = threadIdx.x;
    int base = b * Nn;
    float acc[13];
    #pragma unroll
    for (int k = 0; k < 13; ++k) acc[k] = 0.f;
    for (int i = t; i < Nn; i += 256) {
        float u = ua[base + i], uod = uoda[base + i], df = dflat[base + i], d2 = d2a[base + i];
        float r1 = r1a[base + i], r2 = r2a[base + i], q1 = q1a[base + i], q2 = q2a[base + i];
        float s0 = s0a[base + i], s1 = s1a[base + i];
        acc[0] += u * r1;                 // a_scal
        acc[1] += uod * r2;               // s_scal
        acc[2] += df * uod * uod;         // num part A
        acc[3] += uod * r1;               // num part B
        acc[4] += d2 * d2 * (1.0f / 1024.0f);  // den = sum (u*d2)^2
        acc[5] += s0 * q1;                // out_adj 00
        acc[6] += s0 * q2;                // 01
        acc[7] += s1 * q1;                // 10
        acc[8] += s1 * q2;                // 11
        acc[9] += df * (s0 * s0 + s1 * s1);    // mincut_den
        acc[10] += s0 * s0;
        acc[11] += s0 * s1;
        acc[12] += s1 * s1;
    }
    __shared__ float red[4][13];
    int w = t >> 6, lane = t & 63;
    #pragma unroll
    for (int k = 0; k < 13; ++k) {
        acc[k] = wave_sum(acc[k]);
        if (lane == 0) red[w][k] = acc[k];
    }
    __syncthreads();
    if (t == 0) {
        float v[13];
        #pragma unroll
        for (int k = 0; k < 13; ++k) v[k] = red[0][k] + red[1][k] + red[2][k] + red[3][k];
        float num = v[2] - v[3];
        float f = 1024.0f * fabsf(num / (v[4] + EPSf));
        float as = v[0] + v[1];
        coefP[b] = -4.0f * f * as;
        m8f[b] = -8.0f * f;
        outp[OA_OFF + b * 4 + 0] = v[5];
        outp[OA_OFF + b * 4 + 1] = v[6];
        outp[OA_OFF + b * 4 + 2] = v[7];
        outp[OA_OFF + b * 4 + 3] = v[8];
        mcp[b] = -((v[5] + v[8]) / v[9]);
        float ss00 = v[10], ss01 = v[11], ss11 = v[12];
        float nrm = sqrtf(ss00 * ss00 + 2.f * ss01 * ss01 + ss11 * ss11);
        float is = 0.7071067811865475f;
        float d00 = ss00 / nrm - is, d01 = ss01 / nrm, d11 = ss11 / nrm - is;
        orp[b] = sqrtf(d00 * d00 + 2.f * d01 * d01 + d11 * d11);
    }
}

// ---- K4b: average loss parts ----
__global__ void k_final(const float* __restrict__ mcp, const float* __restrict__ orp,
                        float* __restrict__ outp) {
    int t = threadIdx.x;  // 64
    float m = (t < 32) ? mcp[t] : 0.f;
    float o = (t < 32) ? orp[t] : 0.f;
    m = wave_sum(m); o = wave_sum(o);
    if (t == 0) { outp[MC_OFF] = m * (1.0f / 32.0f); outp[OR_OFF] = o * (1.0f / 32.0f); }
}

// ---- K5a: pooled feature partials. 64 chunks of 16 rows per batch ----
__global__ void k_pool_a(const float* __restrict__ x, const float* __restrict__ s0a,
                         const float* __restrict__ s1a, float* __restrict__ pp) {
    int c = blockIdx.x, b = blockIdx.y, f = threadIdx.x;  // 64 x 32, 128 threads
    const float* xb = x + (size_t)b * Nn * Ff;
    float a0 = 0.f, a1 = 0.f;
    int n0 = c * 16;
    #pragma unroll 4
    for (int n = n0; n < n0 + 16; ++n) {
        float xv = xb[(size_t)n * Ff + f];
        a0 += s0a[b * Nn + n] * xv;
        a1 += s1a[b * Nn + n] * xv;
    }
    pp[((size_t)(b * 64 + c) * 2 + 0) * Ff + f] = a0;
    pp[((size_t)(b * 64 + c) * 2 + 1) * Ff + f] = a1;
}

// ---- K5b: reduce pooled partials -> d_out ----
__global__ void k_pool_b(const float* __restrict__ pp, float* __restrict__ outp) {
    int b = blockIdx.x, t = threadIdx.x;  // 256
    int k = t >> 7, f = t & 127;
    float acc = 0.f;
    #pragma unroll
    for (int c = 0; c < 64; ++c) acc += pp[((size_t)(b * 64 + c) * 2 + k) * Ff + f];
    outp[OUT_OFF + b * 256 + k * Ff + f] = acc;
}

// ---- K6: one rewiring iteration. State S = Ac - adj (S=0 at iter1). ----
// 512 threads = 8 waves, 2 rows each -> 16 waves/CU at 74 KB LDS (2 blocks/CU).
__global__ __launch_bounds__(512, 4) void k_iter(
    const float* __restrict__ Ssrc,   // null on iter 1 (S == 0)
    float* __restrict__ dst,
    const float* __restrict__ adj,
    const float* __restrict__ ddera, const float* __restrict__ uoda,
    const float* __restrict__ coefP, const float* __restrict__ m8f,
    int finalIter) {
    __shared__ float T[16][1028];     // T[ii][j] = S[b, j, r0+ii]  (transpose slice)
    __shared__ float dd_s[Nn];
    __shared__ float q_s[Nn];
    int b = blockIdx.y, rb = blockIdx.x, r0 = rb * 16;
    int t = threadIdx.x;
    if (t < 256) {
        float4 dv = *(const float4*)(ddera + b * Nn + (t << 2));
        float4 qv = *(const float4*)(uoda + b * Nn + (t << 2));
        *(float4*)(&dd_s[t << 2]) = dv;
        *(float4*)(&q_s[t << 2]) = qv;
    }
    const size_t mb = (size_t)b * Nn * Nn;
    if (Ssrc) {
        const float* Sb = Ssrc + mb;
        #pragma unroll
        for (int k = 0; k < 8; ++k) {
            int qi = t + 512 * k;
            int j = qi >> 2, i4 = (qi & 3) << 2;
            float4 v = *(const float4*)(Sb + (size_t)j * Nn + r0 + i4);
            T[i4 + 0][j] = v.x; T[i4 + 1][j] = v.y; T[i4 + 2][j] = v.z; T[i4 + 3][j] = v.w;
        }
    } else {
        #pragma unroll
        for (int k = 0; k < 8; ++k) {
            int qi = t + 512 * k;
            int j = qi >> 2, i4 = (qi & 3) << 2;
            T[i4 + 0][j] = 0.f; T[i4 + 1][j] = 0.f; T[i4 + 2][j] = 0.f; T[i4 + 3][j] = 0.f;
        }
    }
    __syncthreads();
    float cP = coefP[b], m8 = m8f[b];
    int w = t >> 6, lane = t & 63;
    const float* adjB = adj + mb;
    float* dstB = dst + mb;
    for (int rr = 0; rr < 2; ++rr) {
        int i = (w << 1) + rr;
        int gi = r0 + i;
        const float* Arow = adjB + (size_t)gi * Nn;
        const float* Srow = Ssrc ? Ssrc + mb + (size_t)gi * Nn : nullptr;
        float ddi = dd_s[gi], qi_ = q_s[gi];
        float4 Lv[4], Av[4];
        float mx = -3.4e38f;
        #pragma unroll
        for (int cc = 0; cc < 4; ++cc) {
            int j0 = cc * 256 + (lane << 2);
            float4 a = *(const float4*)(Arow + j0);
            float4 s;
            if (Srow) s = *(const float4*)(Srow + j0);
            else s = make_float4(0.f, 0.f, 0.f, 0.f);
            float4 tr = *(const float4*)(&T[i][j0]);
            float4 ddj = *(const float4*)(&dd_s[j0]);
            float4 qj = *(const float4*)(&q_s[j0]);
            float4 L;
            {
                float G = 2.f * s.x + 2.f * tr.x + cP * (ddi + ddj.x) + m8 * qi_ * qj.x;
                if (j0 + 0 == gi) G *= 0.5f;
                L.x = (s.x + a.x) - MUf * G;
            }
            {
                float G = 2.f * s.y + 2.f * tr.y + cP * (ddi + ddj.y) + m8 * qi_ * qj.y;
                if (j0 + 1 == gi) G *= 0.5f;
                L.y = (s.y + a.y) - MUf * G;
            }
            {
                float G = 2.f * s.z + 2.f * tr.z + cP * (ddi + ddj.z) + m8 * qi_ * qj.z;
                if (j0 + 2 == gi) G *= 0.5f;
                L.z = (s.z + a.z) - MUf * G;
            }
            {
                float G = 2.f * s.w + 2.f * tr.w + cP * (ddi + ddj.w) + m8 * qi_ * qj.w;
                if (j0 + 3 == gi) G *= 0.5f;
                L.w = (s.w + a.w) - MUf * G;
            }
            Av[cc] = a; Lv[cc] = L;
            mx = fmaxf(mx, fmaxf(fmaxf(L.x, L.y), fmaxf(L.z, L.w)));
        }
        mx = wave_max(mx);
        float sum = 0.f;
        #pragma unroll
        for (int cc = 0; cc < 4; ++cc) {
            Lv[cc].x = __expf(Lv[cc].x - mx);
            Lv[cc].y = __expf(Lv[cc].y - mx);
            Lv[cc].z = __expf(Lv[cc].z - mx);
            Lv[cc].w = __expf(Lv[cc].w - mx);
            sum += Lv[cc].x + Lv[cc].y + Lv[cc].z + Lv[cc].w;
        }
        sum = wave_sum(sum);
        float inv = 1.0f / sum;
        #pragma unroll
        for (int cc = 0; cc < 4; ++cc) {
            int j0 = cc * 256 + (lane << 2);
            float4 o;
            o.x = Lv[cc].x * inv * Av[cc].x;
            o.y = Lv[cc].y * inv * Av[cc].y;
            o.z = Lv[cc].z * inv * Av[cc].z;
            o.w = Lv[cc].w * inv * Av[cc].w;
            if (!finalIter) {   // store S = Ac_new - adj
                o.x -= Av[cc].x; o.y -= Av[cc].y; o.z -= Av[cc].z; o.w -= Av[cc].w;
            }
            *(float4*)(dstB + (size_t)gi * Nn + j0) = o;
        }
    }
}

extern "C" void kernel_launch(void* const* d_in, const int* in_sizes, int n_in,
                              void* d_out, int out_size, void* d_ws, size_t ws_size,
                              hipStream_t stream) {
    const float* x = (const float*)d_in[0];
    const float* adj = (const float*)d_in[1];
    const float* s_in = (const float*)d_in[2];
    float* out = (float*)d_out;
    float* ws = (float*)d_ws;

    float* S = ws;                         // MAT floats (128 MiB)
    float* pp = ws;                        // pool partials alias S (consumed before S written)
    float* vb = ws + (size_t)MAT;
    float* dflat = vb + 0 * (size_t)Vv;
    float* s0 = vb + 1 * (size_t)Vv;
    float* s1 = vb + 2 * (size_t)Vv;
    float* u  = vb + 3 * (size_t)Vv;
    float* uod = vb + 4 * (size_t)Vv;
    float* d2 = vb + 5 * (size_t)Vv;
    float* dder = vb + 6 * (size_t)Vv;
    float* r1 = vb + 7 * (size_t)Vv;
    float* r2 = vb + 8 * (size_t)Vv;
    float* q1 = vb + 9 * (size_t)Vv;
    float* q2 = vb + 10 * (size_t)Vv;
    float* coefP = vb + 11 * (size_t)Vv;
    float* m8f = coefP + 32;
    float* mcp = coefP + 64;
    float* orp = coefP + 96;
    float* outAc = out + AC_OFF;

    k_rowsum<<<8192, 256, 0, stream>>>(adj, dflat);
    k_vectors<<<128, 256, 0, stream>>>(s_in, dflat, s0, s1, u, uod, d2, dder);
    k_matvec<<<8192, 256, 0, stream>>>(adj, uod, u, s0, s1, r1, r2, q1, q2);
    k_batchred<<<32, 256, 0, stream>>>(dflat, s0, s1, u, uod, d2, r1, r2, q1, q2,
                                       out, coefP, m8f, mcp, orp);
    k_final<<<1, 64, 0, stream>>>(mcp, orp, out);
    k_pool_a<<<dim3(64, 32), 128, 0, stream>>>(x, s0, s1, pp);
    k_pool_b<<<32, 256, 0, stream>>>(pp, out);

    dim3 ig(64, 32);
    // iter1: S==0 -> write S1 into d_out Ac region (scratch)
    k_iter<<<ig, 512, 0, stream>>>(nullptr, outAc, adj, dder, uod, coefP, m8f, 0);
    // iter2: outAc -> ws.S
    k_iter<<<ig, 512, 0, stream>>>(outAc, S, adj, dder, uod, coefP, m8f, 0);
    // iter3: ws.S -> outAc
    k_iter<<<ig, 512, 0, stream>>>(S, outAc, adj, dder, uod, coefP, m8f, 0);
    // iter4: outAc -> ws.S
    k_iter<<<ig, 512, 0, stream>>>(outAc, S, adj, dder, uod, coefP, m8f, 0);
    // iter5 (final): ws.S -> outAc, write true Ac
    k_iter<<<ig, 512, 0, stream>>>(S, outAc, adj, dder, uod, coefP, m8f, 1);
}

// Round 3
// 653.952 us; speedup vs baseline: 1.0998x; 1.0998x over previous
//
#include <hip/hip_runtime.h>
#include <cstddef>

#define Nn 1024
#define Bb 32
#define Ff 128
#define Vv 32768            // B*N
#define MAT 33554432        // B*N*N
#define OUT_OFF 0
#define AC_OFF 8192
#define OA_OFF (8192 + 33554432)
#define MC_OFF (OA_OFF + 128)
#define OR_OFF (MC_OFF + 1)
#define EPSf 1e-15f
#define MUf 0.01f

__device__ __forceinline__ float wave_sum(float v) {
    #pragma unroll
    for (int off = 32; off; off >>= 1) v += __shfl_xor(v, off, 64);
    return v;
}
__device__ __forceinline__ float wave_max(float v) {
    #pragma unroll
    for (int off = 32; off; off >>= 1) v = fmaxf(v, __shfl_xor(v, off, 64));
    return v;
}

// ---- K1: row sums of adj -> d_flat, fused per-node vectors ----
__global__ void k_rowsumvec(const float* __restrict__ adj, const float* __restrict__ s_in,
                            float* __restrict__ dflat,
                            float* __restrict__ s0a, float* __restrict__ s1a,
                            float* __restrict__ ua, float* __restrict__ uoda,
                            float* __restrict__ d2a, float* __restrict__ ddera) {
    int w = threadIdx.x >> 6, lane = threadIdx.x & 63;
    int row = blockIdx.x * 4 + w;          // 0..32767
    const float* r = adj + (size_t)row * Nn;
    float acc = 0.f;
    #pragma unroll
    for (int cc = 0; cc < 4; ++cc) {
        float4 v = *(const float4*)(r + cc * 256 + (lane << 2));
        acc += v.x + v.y + v.z + v.w;
    }
    acc = wave_sum(acc);
    if (lane == 0) {
        float df = acc;
        dflat[row] = df;
        float l0 = s_in[2 * row], l1 = s_in[2 * row + 1];
        float m = fmaxf(l0, l1);
        float e0 = __expf(l0 - m), e1 = __expf(l1 - m);
        float Z = e0 + e1;
        s0a[row] = e0 / Z; s1a[row] = e1 / Z;
        float u = (l1 > l0) ? -0.03125f : 0.03125f;
        float d2 = sqrtf(df + EPSf) + EPSf;
        float uod = u / d2;
        ua[row] = u; uoda[row] = uod; d2a[row] = d2;
        ddera[row] = -0.5f * d2 / (df + EPSf);
    }
}

// ---- K3: per-row matvecs r1=A.uod r2=A.u q1=A.s0 q2=A.s1. wave per row ----
__global__ void k_matvec(const float* __restrict__ adj,
                         const float* __restrict__ uoda, const float* __restrict__ ua,
                         const float* __restrict__ s0a, const float* __restrict__ s1a,
                         float* __restrict__ r1a, float* __restrict__ r2a,
                         float* __restrict__ q1a, float* __restrict__ q2a) {
    int w = threadIdx.x >> 6, lane = threadIdx.x & 63;
    int row = blockIdx.x * 4 + w;
    int b = row >> 10;
    const float* r = adj + (size_t)row * Nn;
    const float* uodB = uoda + b * Nn;
    const float* uB = ua + b * Nn;
    const float* s0B = s0a + b * Nn;
    const float* s1B = s1a + b * Nn;
    float a1 = 0.f, a2 = 0.f, a3 = 0.f, a4 = 0.f;
    #pragma unroll
    for (int cc = 0; cc < 4; ++cc) {
        int j0 = cc * 256 + (lane << 2);
        float4 av = *(const float4*)(r + j0);
        float4 uo = *(const float4*)(uodB + j0);
        float4 uu = *(const float4*)(uB + j0);
        float4 v0 = *(const float4*)(s0B + j0);
        float4 v1 = *(const float4*)(s1B + j0);
        a1 += av.x * uo.x + av.y * uo.y + av.z * uo.z + av.w * uo.w;
        a2 += av.x * uu.x + av.y * uu.y + av.z * uu.z + av.w * uu.w;
        a3 += av.x * v0.x + av.y * v0.y + av.z * v0.z + av.w * v0.w;
        a4 += av.x * v1.x + av.y * v1.y + av.z * v1.z + av.w * v1.w;
    }
    a1 = wave_sum(a1); a2 = wave_sum(a2); a3 = wave_sum(a3); a4 = wave_sum(a4);
    if (lane == 0) { r1a[row] = a1; r2a[row] = a2; q1a[row] = a3; q2a[row] = a4; }
}

// ---- K4: per-batch reductions -> f, coefP, m8f, out_adj, loss parts ----
__global__ void k_batchred(const float* __restrict__ dflat, const float* __restrict__ s0a,
                           const float* __restrict__ s1a, const float* __restrict__ ua,
                           const float* __restrict__ uoda, const float* __restrict__ d2a,
                           const float* __restrict__ r1a, const float* __restrict__ r2a,
                           const float* __restrict__ q1a, const float* __restrict__ q2a,
                           float* __restrict__ outp, float* __restrict__ coefP,
                           float* __restrict__ m8f, float* __restrict__ mcp,
                           float* __restrict__ orp) {
    int b = blockIdx.x, t = threadIdx.x;
    int base = b * Nn;
    float acc[13];
    #pragma unroll
    for (int k = 0; k < 13; ++k) acc[k] = 0.f;
    for (int i = t; i < Nn; i += 256) {
        float u = ua[base + i], uod = uoda[base + i], df = dflat[base + i], d2 = d2a[base + i];
        float r1 = r1a[base + i], r2 = r2a[base + i], q1 = q1a[base + i], q2 = q2a[base + i];
        float s0 = s0a[base + i], s1 = s1a[base + i];
        acc[0] += u * r1;
        acc[1] += uod * r2;
        acc[2] += df * uod * uod;
        acc[3] += uod * r1;
        acc[4] += d2 * d2 * (1.0f / 1024.0f);
        acc[5] += s0 * q1;
        acc[6] += s0 * q2;
        acc[7] += s1 * q1;
        acc[8] += s1 * q2;
        acc[9] += df * (s0 * s0 + s1 * s1);
        acc[10] += s0 * s0;
        acc[11] += s0 * s1;
        acc[12] += s1 * s1;
    }
    __shared__ float red[4][13];
    int w = t >> 6, lane = t & 63;
    #pragma unroll
    for (int k = 0; k < 13; ++k) {
        acc[k] = wave_sum(acc[k]);
        if (lane == 0) red[w][k] = acc[k];
    }
    __syncthreads();
    if (t == 0) {
        float v[13];
        #pragma unroll
        for (int k = 0; k < 13; ++k) v[k] = red[0][k] + red[1][k] + red[2][k] + red[3][k];
        float num = v[2] - v[3];
        float f = 1024.0f * fabsf(num / (v[4] + EPSf));
        float as = v[0] + v[1];
        coefP[b] = -4.0f * f * as;
        m8f[b] = -8.0f * f;
        outp[OA_OFF + b * 4 + 0] = v[5];
        outp[OA_OFF + b * 4 + 1] = v[6];
        outp[OA_OFF + b * 4 + 2] = v[7];
        outp[OA_OFF + b * 4 + 3] = v[8];
        mcp[b] = -((v[5] + v[8]) / v[9]);
        float ss00 = v[10], ss01 = v[11], ss11 = v[12];
        float nrm = sqrtf(ss00 * ss00 + 2.f * ss01 * ss01 + ss11 * ss11);
        float is = 0.7071067811865475f;
        float d00 = ss00 / nrm - is, d01 = ss01 / nrm, d11 = ss11 / nrm - is;
        orp[b] = sqrtf(d00 * d00 + 2.f * d01 * d01 + d11 * d11);
    }
}

// ---- K4b: average loss parts ----
__global__ void k_final(const float* __restrict__ mcp, const float* __restrict__ orp,
                        float* __restrict__ outp) {
    int t = threadIdx.x;  // 64
    float m = (t < 32) ? mcp[t] : 0.f;
    float o = (t < 32) ? orp[t] : 0.f;
    m = wave_sum(m); o = wave_sum(o);
    if (t == 0) { outp[MC_OFF] = m * (1.0f / 32.0f); outp[OR_OFF] = o * (1.0f / 32.0f); }
}

// ---- K5a: pooled feature partials. 64 chunks of 16 rows per batch ----
__global__ void k_pool_a(const float* __restrict__ x, const float* __restrict__ s0a,
                         const float* __restrict__ s1a, float* __restrict__ pp) {
    int c = blockIdx.x, b = blockIdx.y, f = threadIdx.x;  // 64 x 32, 128 threads
    const float* xb = x + (size_t)b * Nn * Ff;
    float a0 = 0.f, a1 = 0.f;
    int n0 = c * 16;
    #pragma unroll 4
    for (int n = n0; n < n0 + 16; ++n) {
        float xv = xb[(size_t)n * Ff + f];
        a0 += s0a[b * Nn + n] * xv;
        a1 += s1a[b * Nn + n] * xv;
    }
    pp[((size_t)(b * 64 + c) * 2 + 0) * Ff + f] = a0;
    pp[((size_t)(b * 64 + c) * 2 + 1) * Ff + f] = a1;
}

// ---- K5b: reduce pooled partials -> d_out ----
__global__ void k_pool_b(const float* __restrict__ pp, float* __restrict__ outp) {
    int b = blockIdx.x, t = threadIdx.x;  // 256
    int k = t >> 7, f = t & 127;
    float acc = 0.f;
    #pragma unroll
    for (int c = 0; c < 64; ++c) acc += pp[((size_t)(b * 64 + c) * 2 + k) * Ff + f];
    outp[OUT_OFF + b * 256 + k * Ff + f] = acc;
}

// ---- K6: one rewiring iteration, S kept in 8-row PANEL layout between iters.
// Panel layout: S[b, i, j] at b*N*N + (i>>3)*8192 + j*8 + (i&7).
// Block = (rb in [0,128), b). Owns rows gi = rb*8 .. rb*8+7 and columns c0=rb*8..+7
// for the transpose slice. All global S traffic is >=256B contiguous.
__global__ __launch_bounds__(256, 2) void k_iter(
    const float* __restrict__ Ssrc,   // panel layout; null on iter 1 (S == 0)
    float* __restrict__ dst,          // panel layout (iters 1-4) or natural (final)
    const float* __restrict__ adj,
    const float* __restrict__ ddera, const float* __restrict__ uoda,
    const float* __restrict__ coefP, const float* __restrict__ m8f,
    int finalIter) {
    __shared__ float lds[16424];   // SownR[8][1025] @0, T[8][1028] @8200; W[1024][9] aliases @0
    __shared__ float dd_s[Nn];
    __shared__ float q_s[Nn];
    float* SownR = lds;            // SownR[ii][j] = S[b, c0+ii, j]
    float* T = lds + 8200;         // T[dc][i]    = S[b, i, c0+dc]
    float* W = lds;                // W[j][ii]    = S_new[b, c0+ii, j] (panel order)
    int b = blockIdx.y, rb = blockIdx.x;
    int c0 = rb * 8;
    int t = threadIdx.x;
    {
        float4 dv = *(const float4*)(ddera + b * Nn + (t << 2));
        float4 qv = *(const float4*)(uoda + b * Nn + (t << 2));
        *(float4*)(&dd_s[t << 2]) = dv;
        *(float4*)(&q_s[t << 2]) = qv;
    }
    const size_t mb = (size_t)b * Nn * Nn;
    if (Ssrc) {
        const float* Sb = Ssrc + mb;
        // own panel (32 KB contiguous) -> SownR  (transpose to row-major in LDS)
        #pragma unroll
        for (int k = 0; k < 8; ++k) {
            int q = t + 256 * k;                    // 2048 float4s
            float4 v = *(const float4*)(Sb + rb * 8192 + q * 4);
            int j = q >> 1, ii = (q & 1) * 4;
            SownR[(ii + 0) * 1025 + j] = v.x;
            SownR[(ii + 1) * 1025 + j] = v.y;
            SownR[(ii + 2) * 1025 + j] = v.z;
            SownR[(ii + 3) * 1025 + j] = v.w;
        }
        // transpose slices: 128 chunks of 256B contiguous -> T
        #pragma unroll
        for (int k = 0; k < 8; ++k) {
            int q = t + 256 * k;
            int ip = q >> 4, off4 = q & 15;         // chunk = panel ip, 16 float4s
            float4 v = *(const float4*)(Sb + ip * 8192 + c0 * 8 + off4 * 4);
            int dc = off4 >> 1, ii = (q & 1) * 4;
            *(float4*)(&T[dc * 1028 + ip * 8 + ii]) = v;
        }
    }
    __syncthreads();
    float cP = coefP[b], m8 = m8f[b];
    int w = t >> 6, lane = t & 63;
    const float* adjB = adj + mb;
    float4 res[2][4];
    for (int rr = 0; rr < 2; ++rr) {
        int i = (w << 1) + rr;
        int gi = c0 + i;
        const float* Arow = adjB + (size_t)gi * Nn;
        float ddi = dd_s[gi], qi_ = q_s[gi];
        float4 Lv[4], Av[4];
        float mx = -3.4e38f;
        #pragma unroll
        for (int cc = 0; cc < 4; ++cc) {
            int j0 = cc * 256 + (lane << 2);
            float4 a = *(const float4*)(Arow + j0);
            float4 s, tr;
            if (Ssrc) {
                s  = *(const float4*)(&SownR[i * 1025 + j0]);
                tr = *(const float4*)(&T[i * 1028 + j0]);
            } else {
                s = make_float4(0.f, 0.f, 0.f, 0.f); tr = s;
            }
            float4 ddj = *(const float4*)(&dd_s[j0]);
            float4 qj = *(const float4*)(&q_s[j0]);
            float4 L;
            {
                float G = 2.f * s.x + 2.f * tr.x + cP * (ddi + ddj.x) + m8 * qi_ * qj.x;
                if (j0 + 0 == gi) G *= 0.5f;
                L.x = (s.x + a.x) - MUf * G;
            }
            {
                float G = 2.f * s.y + 2.f * tr.y + cP * (ddi + ddj.y) + m8 * qi_ * qj.y;
                if (j0 + 1 == gi) G *= 0.5f;
                L.y = (s.y + a.y) - MUf * G;
            }
            {
                float G = 2.f * s.z + 2.f * tr.z + cP * (ddi + ddj.z) + m8 * qi_ * qj.z;
                if (j0 + 2 == gi) G *= 0.5f;
                L.z = (s.z + a.z) - MUf * G;
            }
            {
                float G = 2.f * s.w + 2.f * tr.w + cP * (ddi + ddj.w) + m8 * qi_ * qj.w;
                if (j0 + 3 == gi) G *= 0.5f;
                L.w = (s.w + a.w) - MUf * G;
            }
            Av[cc] = a; Lv[cc] = L;
            mx = fmaxf(mx, fmaxf(fmaxf(L.x, L.y), fmaxf(L.z, L.w)));
        }
        mx = wave_max(mx);
        float sum = 0.f;
        #pragma unroll
        for (int cc = 0; cc < 4; ++cc) {
            Lv[cc].x = __expf(Lv[cc].x - mx);
            Lv[cc].y = __expf(Lv[cc].y - mx);
            Lv[cc].z = __expf(Lv[cc].z - mx);
            Lv[cc].w = __expf(Lv[cc].w - mx);
            sum += Lv[cc].x + Lv[cc].y + Lv[cc].z + Lv[cc].w;
        }
        sum = wave_sum(sum);
        float inv = 1.0f / sum;
        #pragma unroll
        for (int cc = 0; cc < 4; ++cc) {
            float4 o;
            o.x = Lv[cc].x * inv * Av[cc].x;
            o.y = Lv[cc].y * inv * Av[cc].y;
            o.z = Lv[cc].z * inv * Av[cc].z;
            o.w = Lv[cc].w * inv * Av[cc].w;
            if (!finalIter) {   // S = Ac_new - adj
                o.x -= Av[cc].x; o.y -= Av[cc].y; o.z -= Av[cc].z; o.w -= Av[cc].w;
            }
            res[rr][cc] = o;
        }
        if (finalIter) {
            float* drow = dst + mb + (size_t)gi * Nn;
            #pragma unroll
            for (int cc = 0; cc < 4; ++cc) {
                int j0 = cc * 256 + (lane << 2);
                *(float4*)(drow + j0) = res[rr][cc];
            }
        }
    }
    if (!finalIter) {
        __syncthreads();   // done reading SownR/T; W aliases them
        #pragma unroll
        for (int rr = 0; rr < 2; ++rr) {
            int i = (w << 1) + rr;
            #pragma unroll
            for (int cc = 0; cc < 4; ++cc) {
                int j0 = cc * 256 + (lane << 2);
                W[(j0 + 0) * 9 + i] = res[rr][cc].x;
                W[(j0 + 1) * 9 + i] = res[rr][cc].y;
                W[(j0 + 2) * 9 + i] = res[rr][cc].z;
                W[(j0 + 3) * 9 + i] = res[rr][cc].w;
            }
        }
        __syncthreads();
        float* dstB = dst + mb + rb * 8192;   // own panel, contiguous 32 KB
        #pragma unroll
        for (int k = 0; k < 8; ++k) {
            int q = t + 256 * k;
            int j = q >> 1, ii = (q & 1) * 4;
            float4 v;
            v.x = W[j * 9 + ii + 0];
            v.y = W[j * 9 + ii + 1];
            v.z = W[j * 9 + ii + 2];
            v.w = W[j * 9 + ii + 3];
            *(float4*)(dstB + q * 4) = v;
        }
    }
}

extern "C" void kernel_launch(void* const* d_in, const int* in_sizes, int n_in,
                              void* d_out, int out_size, void* d_ws, size_t ws_size,
                              hipStream_t stream) {
    const float* x = (const float*)d_in[0];
    const float* adj = (const float*)d_in[1];
    const float* s_in = (const float*)d_in[2];
    float* out = (float*)d_out;
    float* ws = (float*)d_ws;

    float* S = ws;                         // MAT floats (128 MiB), panel layout
    float* pp = ws;                        // pool partials alias S (consumed before S written)
    float* vb = ws + (size_t)MAT;
    float* dflat = vb + 0 * (size_t)Vv;
    float* s0 = vb + 1 * (size_t)Vv;
    float* s1 = vb + 2 * (size_t)Vv;
    float* u  = vb + 3 * (size_t)Vv;
    float* uod = vb + 4 * (size_t)Vv;
    float* d2 = vb + 5 * (size_t)Vv;
    float* dder = vb + 6 * (size_t)Vv;
    float* r1 = vb + 7 * (size_t)Vv;
    float* r2 = vb + 8 * (size_t)Vv;
    float* q1 = vb + 9 * (size_t)Vv;
    float* q2 = vb + 10 * (size_t)Vv;
    float* coefP = vb + 11 * (size_t)Vv;
    float* m8f = coefP + 32;
    float* mcp = coefP + 64;
    float* orp = coefP + 96;
    float* outAc = out + AC_OFF;

    k_rowsumvec<<<8192, 256, 0, stream>>>(adj, s_in, dflat, s0, s1, u, uod, d2, dder);
    k_matvec<<<8192, 256, 0, stream>>>(adj, uod, u, s0, s1, r1, r2, q1, q2);
    k_batchred<<<32, 256, 0, stream>>>(dflat, s0, s1, u, uod, d2, r1, r2, q1, q2,
                                       out, coefP, m8f, mcp, orp);
    k_final<<<1, 64, 0, stream>>>(mcp, orp, out);
    k_pool_a<<<dim3(64, 32), 128, 0, stream>>>(x, s0, s1, pp);
    k_pool_b<<<32, 256, 0, stream>>>(pp, out);

    dim3 ig(128, 32);
    // iter1: S==0 -> write panel S1 into d_out Ac region (scratch)
    k_iter<<<ig, 256, 0, stream>>>(nullptr, outAc, adj, dder, uod, coefP, m8f, 0);
    // iter2: outAc(panel) -> ws.S(panel)
    k_iter<<<ig, 256, 0, stream>>>(outAc, S, adj, dder, uod, coefP, m8f, 0);
    // iter3: ws.S -> outAc
    k_iter<<<ig, 256, 0, stream>>>(S, outAc, adj, dder, uod, coefP, m8f, 0);
    // iter4: outAc -> ws.S
    k_iter<<<ig, 256, 0, stream>>>(outAc, S, adj, dder, uod, coefP, m8f, 0);
    // iter5 (final): ws.S(panel) -> outAc NATURAL layout, true Ac
    k_iter<<<ig, 256, 0, stream>>>(S, outAc, adj, dder, uod, coefP, m8f, 1);
}

// Round 4
// 624.951 us; speedup vs baseline: 1.1509x; 1.0464x over previous
//
#include <hip/hip_runtime.h>
#include <cstddef>

#define Nn 1024
#define Bb 32
#define Ff 128
#define Vv 32768            // B*N
#define MAT 33554432        // B*N*N
#define OUT_OFF 0
#define AC_OFF 8192
#define OA_OFF (8192 + 33554432)
#define MC_OFF (OA_OFF + 128)
#define OR_OFF (MC_OFF + 1)
#define EPSf 1e-15f
#define MUf 0.01f

__device__ __forceinline__ float wave_sum(float v) {
    #pragma unroll
    for (int off = 32; off; off >>= 1) v += __shfl_xor(v, off, 64);
    return v;
}
__device__ __forceinline__ float wave_max(float v) {
    #pragma unroll
    for (int off = 32; off; off >>= 1) v = fmaxf(v, __shfl_xor(v, off, 64));
    return v;
}

// ---- K1: row sums of adj -> d_flat, fused per-node vectors ----
__global__ void k_rowsumvec(const float* __restrict__ adj, const float* __restrict__ s_in,
                            float* __restrict__ dflat,
                            float* __restrict__ s0a, float* __restrict__ s1a,
                            float* __restrict__ ua, float* __restrict__ uoda,
                            float* __restrict__ d2a, float* __restrict__ ddera) {
    int w = threadIdx.x >> 6, lane = threadIdx.x & 63;
    int row = blockIdx.x * 4 + w;          // 0..32767
    const float* r = adj + (size_t)row * Nn;
    float acc = 0.f;
    #pragma unroll
    for (int cc = 0; cc < 4; ++cc) {
        float4 v = *(const float4*)(r + cc * 256 + (lane << 2));
        acc += v.x + v.y + v.z + v.w;
    }
    acc = wave_sum(acc);
    if (lane == 0) {
        float df = acc;
        dflat[row] = df;
        float l0 = s_in[2 * row], l1 = s_in[2 * row + 1];
        float m = fmaxf(l0, l1);
        float e0 = __expf(l0 - m), e1 = __expf(l1 - m);
        float Z = e0 + e1;
        s0a[row] = e0 / Z; s1a[row] = e1 / Z;
        float u = (l1 > l0) ? -0.03125f : 0.03125f;
        float d2 = sqrtf(df + EPSf) + EPSf;
        float uod = u / d2;
        ua[row] = u; uoda[row] = uod; d2a[row] = d2;
        ddera[row] = -0.5f * d2 / (df + EPSf);
    }
}

// ---- K3: per-row matvecs r1=A.uod r2=A.u q1=A.s0 q2=A.s1. wave per row ----
__global__ void k_matvec(const float* __restrict__ adj,
                         const float* __restrict__ uoda, const float* __restrict__ ua,
                         const float* __restrict__ s0a, const float* __restrict__ s1a,
                         float* __restrict__ r1a, float* __restrict__ r2a,
                         float* __restrict__ q1a, float* __restrict__ q2a) {
    int w = threadIdx.x >> 6, lane = threadIdx.x & 63;
    int row = blockIdx.x * 4 + w;
    int b = row >> 10;
    const float* r = adj + (size_t)row * Nn;
    const float* uodB = uoda + b * Nn;
    const float* uB = ua + b * Nn;
    const float* s0B = s0a + b * Nn;
    const float* s1B = s1a + b * Nn;
    float a1 = 0.f, a2 = 0.f, a3 = 0.f, a4 = 0.f;
    #pragma unroll
    for (int cc = 0; cc < 4; ++cc) {
        int j0 = cc * 256 + (lane << 2);
        float4 av = *(const float4*)(r + j0);
        float4 uo = *(const float4*)(uodB + j0);
        float4 uu = *(const float4*)(uB + j0);
        float4 v0 = *(const float4*)(s0B + j0);
        float4 v1 = *(const float4*)(s1B + j0);
        a1 += av.x * uo.x + av.y * uo.y + av.z * uo.z + av.w * uo.w;
        a2 += av.x * uu.x + av.y * uu.y + av.z * uu.z + av.w * uu.w;
        a3 += av.x * v0.x + av.y * v0.y + av.z * v0.z + av.w * v0.w;
        a4 += av.x * v1.x + av.y * v1.y + av.z * v1.z + av.w * v1.w;
    }
    a1 = wave_sum(a1); a2 = wave_sum(a2); a3 = wave_sum(a3); a4 = wave_sum(a4);
    if (lane == 0) { r1a[row] = a1; r2a[row] = a2; q1a[row] = a3; q2a[row] = a4; }
}

// ---- K4: per-batch reductions -> f, coefP, m8f, out_adj, loss parts ----
__global__ void k_batchred(const float* __restrict__ dflat, const float* __restrict__ s0a,
                           const float* __restrict__ s1a, const float* __restrict__ ua,
                           const float* __restrict__ uoda, const float* __restrict__ d2a,
                           const float* __restrict__ r1a, const float* __restrict__ r2a,
                           const float* __restrict__ q1a, const float* __restrict__ q2a,
                           float* __restrict__ outp, float* __restrict__ coefP,
                           float* __restrict__ m8f, float* __restrict__ mcp,
                           float* __restrict__ orp) {
    int b = blockIdx.x, t = threadIdx.x;
    int base = b * Nn;
    float acc[13];
    #pragma unroll
    for (int k = 0; k < 13; ++k) acc[k] = 0.f;
    for (int i = t; i < Nn; i += 256) {
        float u = ua[base + i], uod = uoda[base + i], df = dflat[base + i], d2 = d2a[base + i];
        float r1 = r1a[base + i], r2 = r2a[base + i], q1 = q1a[base + i], q2 = q2a[base + i];
        float s0 = s0a[base + i], s1 = s1a[base + i];
        acc[0] += u * r1;
        acc[1] += uod * r2;
        acc[2] += df * uod * uod;
        acc[3] += uod * r1;
        acc[4] += d2 * d2 * (1.0f / 1024.0f);
        acc[5] += s0 * q1;
        acc[6] += s0 * q2;
        acc[7] += s1 * q1;
        acc[8] += s1 * q2;
        acc[9] += df * (s0 * s0 + s1 * s1);
        acc[10] += s0 * s0;
        acc[11] += s0 * s1;
        acc[12] += s1 * s1;
    }
    __shared__ float red[4][13];
    int w = t >> 6, lane = t & 63;
    #pragma unroll
    for (int k = 0; k < 13; ++k) {
        acc[k] = wave_sum(acc[k]);
        if (lane == 0) red[w][k] = acc[k];
    }
    __syncthreads();
    if (t == 0) {
        float v[13];
        #pragma unroll
        for (int k = 0; k < 13; ++k) v[k] = red[0][k] + red[1][k] + red[2][k] + red[3][k];
        float num = v[2] - v[3];
        float f = 1024.0f * fabsf(num / (v[4] + EPSf));
        float as = v[0] + v[1];
        coefP[b] = -4.0f * f * as;
        m8f[b] = -8.0f * f;
        outp[OA_OFF + b * 4 + 0] = v[5];
        outp[OA_OFF + b * 4 + 1] = v[6];
        outp[OA_OFF + b * 4 + 2] = v[7];
        outp[OA_OFF + b * 4 + 3] = v[8];
        mcp[b] = -((v[5] + v[8]) / v[9]);
        float ss00 = v[10], ss01 = v[11], ss11 = v[12];
        float nrm = sqrtf(ss00 * ss00 + 2.f * ss01 * ss01 + ss11 * ss11);
        float is = 0.7071067811865475f;
        float d00 = ss00 / nrm - is, d01 = ss01 / nrm, d11 = ss11 / nrm - is;
        orp[b] = sqrtf(d00 * d00 + 2.f * d01 * d01 + d11 * d11);
    }
}

// ---- K4b: average loss parts ----
__global__ void k_final(const float* __restrict__ mcp, const float* __restrict__ orp,
                        float* __restrict__ outp) {
    int t = threadIdx.x;  // 64
    float m = (t < 32) ? mcp[t] : 0.f;
    float o = (t < 32) ? orp[t] : 0.f;
    m = wave_sum(m); o = wave_sum(o);
    if (t == 0) { outp[MC_OFF] = m * (1.0f / 32.0f); outp[OR_OFF] = o * (1.0f / 32.0f); }
}

// ---- K5a: pooled feature partials. 64 chunks of 16 rows per batch ----
__global__ void k_pool_a(const float* __restrict__ x, const float* __restrict__ s0a,
                         const float* __restrict__ s1a, float* __restrict__ pp) {
    int c = blockIdx.x, b = blockIdx.y, f = threadIdx.x;  // 64 x 32, 128 threads
    const float* xb = x + (size_t)b * Nn * Ff;
    float a0 = 0.f, a1 = 0.f;
    int n0 = c * 16;
    #pragma unroll 4
    for (int n = n0; n < n0 + 16; ++n) {
        float xv = xb[(size_t)n * Ff + f];
        a0 += s0a[b * Nn + n] * xv;
        a1 += s1a[b * Nn + n] * xv;
    }
    pp[((size_t)(b * 64 + c) * 2 + 0) * Ff + f] = a0;
    pp[((size_t)(b * 64 + c) * 2 + 1) * Ff + f] = a1;
}

// ---- K5b: reduce pooled partials -> d_out ----
__global__ void k_pool_b(const float* __restrict__ pp, float* __restrict__ outp) {
    int b = blockIdx.x, t = threadIdx.x;  // 256
    int k = t >> 7, f = t & 127;
    float acc = 0.f;
    #pragma unroll
    for (int c = 0; c < 64; ++c) acc += pp[((size_t)(b * 64 + c) * 2 + k) * Ff + f];
    outp[OUT_OFF + b * 256 + k * Ff + f] = acc;
}

// ---- K6: one rewiring iteration, S kept in 8-row PANEL layout between iters.
// Panel layout: S[b, i, j] at b*N*N + (i>>3)*8192 + j*8 + (i&7).
// 512 threads = 8 waves, 1 row/wave -> 16 waves/CU at 2 blocks/CU.
__global__ __launch_bounds__(512, 4) void k_iter(
    const float* __restrict__ Ssrc,   // panel layout; null on iter 1 (S == 0)
    float* __restrict__ dst,          // panel layout (iters 1-4) or natural (final)
    const float* __restrict__ adj,
    const float* __restrict__ ddera, const float* __restrict__ uoda,
    const float* __restrict__ coefP, const float* __restrict__ m8f,
    int finalIter) {
    __shared__ float lds[16424];   // SownR[8][1025] @0, T[8][1028] @8200; W[1024][9] aliases @0
    __shared__ float dd_s[Nn];
    __shared__ float q_s[Nn];
    float* SownR = lds;            // SownR[ii][j] = S[b, c0+ii, j]
    float* T = lds + 8200;         // T[dc][i]    = S[b, i, c0+dc]
    float* W = lds;                // W[j][ii]    = S_new[b, c0+ii, j] (panel order)
    int b = blockIdx.y, rb = blockIdx.x;
    int c0 = rb * 8;
    int t = threadIdx.x;
    if (t < 256) {
        float4 dv = *(const float4*)(ddera + b * Nn + (t << 2));
        float4 qv = *(const float4*)(uoda + b * Nn + (t << 2));
        *(float4*)(&dd_s[t << 2]) = dv;
        *(float4*)(&q_s[t << 2]) = qv;
    }
    const size_t mb = (size_t)b * Nn * Nn;
    if (Ssrc) {
        const float* Sb = Ssrc + mb;
        // own panel (32 KB contiguous) -> SownR  (transpose to row-major in LDS)
        #pragma unroll
        for (int k = 0; k < 4; ++k) {
            int q = t + 512 * k;                    // 2048 float4s
            float4 v = *(const float4*)(Sb + rb * 8192 + q * 4);
            int j = q >> 1, ii = (q & 1) * 4;
            SownR[(ii + 0) * 1025 + j] = v.x;
            SownR[(ii + 1) * 1025 + j] = v.y;
            SownR[(ii + 2) * 1025 + j] = v.z;
            SownR[(ii + 3) * 1025 + j] = v.w;
        }
        // transpose slices: 128 chunks of 256B contiguous -> T
        #pragma unroll
        for (int k = 0; k < 4; ++k) {
            int q = t + 512 * k;
            int ip = q >> 4, off4 = q & 15;         // chunk = panel ip, 16 float4s
            float4 v = *(const float4*)(Sb + ip * 8192 + c0 * 8 + off4 * 4);
            int dc = off4 >> 1, ii = (q & 1) * 4;
            *(float4*)(&T[dc * 1028 + ip * 8 + ii]) = v;
        }
    }
    __syncthreads();
    float cP = coefP[b], m8 = m8f[b];
    int w = t >> 6, lane = t & 63;
    const float* adjB = adj + mb;
    float4 res[4];
    {
        int i = w;
        int gi = c0 + i;
        const float* Arow = adjB + (size_t)gi * Nn;
        float ddi = dd_s[gi], qi_ = q_s[gi];
        float4 Lv[4], Av[4];
        float mx = -3.4e38f;
        #pragma unroll
        for (int cc = 0; cc < 4; ++cc) {
            int j0 = cc * 256 + (lane << 2);
            float4 a = *(const float4*)(Arow + j0);
            float4 s, tr;
            if (Ssrc) {
                s  = *(const float4*)(&SownR[i * 1025 + j0]);
                tr = *(const float4*)(&T[i * 1028 + j0]);
            } else {
                s = make_float4(0.f, 0.f, 0.f, 0.f); tr = s;
            }
            float4 ddj = *(const float4*)(&dd_s[j0]);
            float4 qj = *(const float4*)(&q_s[j0]);
            float4 L;
            {
                float G = 2.f * s.x + 2.f * tr.x + cP * (ddi + ddj.x) + m8 * qi_ * qj.x;
                if (j0 + 0 == gi) G *= 0.5f;
                L.x = (s.x + a.x) - MUf * G;
            }
            {
                float G = 2.f * s.y + 2.f * tr.y + cP * (ddi + ddj.y) + m8 * qi_ * qj.y;
                if (j0 + 1 == gi) G *= 0.5f;
                L.y = (s.y + a.y) - MUf * G;
            }
            {
                float G = 2.f * s.z + 2.f * tr.z + cP * (ddi + ddj.z) + m8 * qi_ * qj.z;
                if (j0 + 2 == gi) G *= 0.5f;
                L.z = (s.z + a.z) - MUf * G;
            }
            {
                float G = 2.f * s.w + 2.f * tr.w + cP * (ddi + ddj.w) + m8 * qi_ * qj.w;
                if (j0 + 3 == gi) G *= 0.5f;
                L.w = (s.w + a.w) - MUf * G;
            }
            Av[cc] = a; Lv[cc] = L;
            mx = fmaxf(mx, fmaxf(fmaxf(L.x, L.y), fmaxf(L.z, L.w)));
        }
        mx = wave_max(mx);
        float sum = 0.f;
        #pragma unroll
        for (int cc = 0; cc < 4; ++cc) {
            Lv[cc].x = __expf(Lv[cc].x - mx);
            Lv[cc].y = __expf(Lv[cc].y - mx);
            Lv[cc].z = __expf(Lv[cc].z - mx);
            Lv[cc].w = __expf(Lv[cc].w - mx);
            sum += Lv[cc].x + Lv[cc].y + Lv[cc].z + Lv[cc].w;
        }
        sum = wave_sum(sum);
        float inv = 1.0f / sum;
        #pragma unroll
        for (int cc = 0; cc < 4; ++cc) {
            float4 o;
            o.x = Lv[cc].x * inv * Av[cc].x;
            o.y = Lv[cc].y * inv * Av[cc].y;
            o.z = Lv[cc].z * inv * Av[cc].z;
            o.w = Lv[cc].w * inv * Av[cc].w;
            if (!finalIter) {   // S = Ac_new - adj
                o.x -= Av[cc].x; o.y -= Av[cc].y; o.z -= Av[cc].z; o.w -= Av[cc].w;
            }
            res[cc] = o;
        }
        if (finalIter) {
            float* drow = dst + mb + (size_t)gi * Nn;
            #pragma unroll
            for (int cc = 0; cc < 4; ++cc) {
                int j0 = cc * 256 + (lane << 2);
                *(float4*)(drow + j0) = res[cc];
            }
        }
    }
    if (!finalIter) {
        __syncthreads();   // done reading SownR/T; W aliases them
        {
            int i = w;
            #pragma unroll
            for (int cc = 0; cc < 4; ++cc) {
                int j0 = cc * 256 + (lane << 2);
                W[(j0 + 0) * 9 + i] = res[cc].x;
                W[(j0 + 1) * 9 + i] = res[cc].y;
                W[(j0 + 2) * 9 + i] = res[cc].z;
                W[(j0 + 3) * 9 + i] = res[cc].w;
            }
        }
        __syncthreads();
        float* dstB = dst + mb + rb * 8192;   // own panel, contiguous 32 KB
        #pragma unroll
        for (int k = 0; k < 4; ++k) {
            int q = t + 512 * k;
            int j = q >> 1, ii = (q & 1) * 4;
            float4 v;
            v.x = W[j * 9 + ii + 0];
            v.y = W[j * 9 + ii + 1];
            v.z = W[j * 9 + ii + 2];
            v.w = W[j * 9 + ii + 3];
            *(float4*)(dstB + q * 4) = v;
        }
    }
}

extern "C" void kernel_launch(void* const* d_in, const int* in_sizes, int n_in,
                              void* d_out, int out_size, void* d_ws, size_t ws_size,
                              hipStream_t stream) {
    const float* x = (const float*)d_in[0];
    const float* adj = (const float*)d_in[1];
    const float* s_in = (const float*)d_in[2];
    float* out = (float*)d_out;
    float* ws = (float*)d_ws;

    float* S = ws;                         // MAT floats (128 MiB), panel layout
    float* pp = ws;                        // pool partials alias S (consumed before S written)
    float* vb = ws + (size_t)MAT;
    float* dflat = vb + 0 * (size_t)Vv;
    float* s0 = vb + 1 * (size_t)Vv;
    float* s1 = vb + 2 * (size_t)Vv;
    float* u  = vb + 3 * (size_t)Vv;
    float* uod = vb + 4 * (size_t)Vv;
    float* d2 = vb + 5 * (size_t)Vv;
    float* dder = vb + 6 * (size_t)Vv;
    float* r1 = vb + 7 * (size_t)Vv;
    float* r2 = vb + 8 * (size_t)Vv;
    float* q1 = vb + 9 * (size_t)Vv;
    float* q2 = vb + 10 * (size_t)Vv;
    float* coefP = vb + 11 * (size_t)Vv;
    float* m8f = coefP + 32;
    float* mcp = coefP + 64;
    float* orp = coefP + 96;
    float* outAc = out + AC_OFF;

    k_rowsumvec<<<8192, 256, 0, stream>>>(adj, s_in, dflat, s0, s1, u, uod, d2, dder);
    k_matvec<<<8192, 256, 0, stream>>>(adj, uod, u, s0, s1, r1, r2, q1, q2);
    k_batchred<<<32, 256, 0, stream>>>(dflat, s0, s1, u, uod, d2, r1, r2, q1, q2,
                                       out, coefP, m8f, mcp, orp);
    k_final<<<1, 64, 0, stream>>>(mcp, orp, out);
    k_pool_a<<<dim3(64, 32), 128, 0, stream>>>(x, s0, s1, pp);
    k_pool_b<<<32, 256, 0, stream>>>(pp, out);

    dim3 ig(128, 32);
    // iter1: S==0 -> write panel S1 into d_out Ac region (scratch)
    k_iter<<<ig, 512, 0, stream>>>(nullptr, outAc, adj, dder, uod, coefP, m8f, 0);
    // iter2: outAc(panel) -> ws.S(panel)
    k_iter<<<ig, 512, 0, stream>>>(outAc, S, adj, dder, uod, coefP, m8f, 0);
    // iter3: ws.S -> outAc
    k_iter<<<ig, 512, 0, stream>>>(S, outAc, adj, dder, uod, coefP, m8f, 0);
    // iter4: outAc -> ws.S
    k_iter<<<ig, 512, 0, stream>>>(outAc, S, adj, dder, uod, coefP, m8f, 0);
    // iter5 (final): ws.S(panel) -> outAc NATURAL layout, true Ac
    k_iter<<<ig, 512, 0, stream>>>(S, outAc, adj, dder, uod, coefP, m8f, 1);
}